// Round 19
// baseline (112.449 us; speedup 1.0000x reference)
//
#include <hip/hip_runtime.h>
#include <hip/hip_fp16.h>

typedef float f4 __attribute__((ext_vector_type(4)));
typedef float f2 __attribute__((ext_vector_type(2)));
typedef _Float16 f16x8 __attribute__((ext_vector_type(8)));
typedef float f32x16 __attribute__((ext_vector_type(16)));

#define NPIX (32*512*512)        // 8388608
#define BN_EPS 1e-5f

// ws float layout (memset clears first 8192 bytes = floats 0..2047):
// [0..26]   reduced M1/M2 moment sums (written by k_stats1 phase A)
// [27] S1, [28] S2 (written by k_redS)
// [64..95]  w2pad[32]
// [96..352) A'-fragment per lane: 64 x uint4 (f16x8 bit patterns)
// [1024]    zbuf rows (reads floats 1024..1535)
// S1 partials at ws[2048+bid], S2 partials at ws[4096+bid] (fully overwritten).
// k_moments block partials live in d_out[i*2048 + bid] (overwritten by opre later).

// ------- k_moments: MFMA Gram matrix of stencil channels (2 tiles/barrier) -------
__global__ __launch_bounds__(256) void k_moments(const float* __restrict__ x,
                                                 const float* __restrict__ ws,
                                                 float* __restrict__ outp) {
    __shared__ ushort sl[4][8][128];  // [wave][channel][pixel] f16
    __shared__ float mom[4][7][7];
    int t = threadIdx.x;
    int l = t & 63, wv = t >> 6;
    int h = l >> 5;
    const float* zb = ws + 1024;

    // ones / zero channel rows (written once)
    sl[wv][6][l]      = (ushort)0x3C00;   // 1.0h
    sl[wv][6][l + 64] = (ushort)0x3C00;
    sl[wv][7][l]      = (ushort)0;
    sl[wv][7][l + 64] = (ushort)0;

    f32x16 accA, accB;
    #pragma unroll
    for (int r = 0; r < 16; ++r) { accA[r] = 0.f; accB[r] = 0.f; }

    int arow = ((l & 31) < 7) ? (l & 31) : 7;          // rows >=7 read the zero row
    const ushort* rbase = &sl[wv][arow][8*h];

    int wave_id = blockIdx.x * 4 + wv;                 // 8192 waves x 2 rows
    #pragma unroll 1
    for (int rr = 0; rr < 2; ++rr) {
        int row = wave_id * 2 + rr;
        int i = row & 511;
        const float* xr = x + row * 512;
        const float* xn = (i > 0)   ? xr - 512 : zb;
        const float* xs = (i < 511) ? xr + 512 : zb;
        #pragma unroll 1
        for (int it = 0; it < 4; ++it) {
            #pragma unroll
            for (int half = 0; half < 2; ++half) {
                int col = it * 128 + half * 64 + l;
                bool okw = (col > 0), oke = (col < 511);
                int cm = okw ? col - 1 : 0;
                int cp = oke ? col + 1 : 511;
                float C  = xr[col], N = xn[col], S_ = xs[col];
                float W_ = xr[cm],  E = xr[cp];
                float NW = xn[cm],  SE = xs[cp];
                W_ = okw ? W_ : 0.f; NW = okw ? NW : 0.f;
                E  = oke ? E  : 0.f; SE = oke ? SE : 0.f;

                float s0 = C;
                float s1 = (S_ - N) * 0.5f;
                float s2 = (E - W_) * 0.5f;
                float s3 = S_ + N - 2.f*C;
                float s4 = E + W_ - 2.f*C;
                float s5 = SE + NW - S_ - E;

                int px = half * 64 + l;
                __half h0 = __float2half(s0), h1 = __float2half(s1);
                __half h2 = __float2half(s2), h3 = __float2half(s3);
                __half h4 = __float2half(s4), h5 = __float2half(s5);
                sl[wv][0][px] = *(ushort*)&h0;
                sl[wv][1][px] = *(ushort*)&h1;
                sl[wv][2][px] = *(ushort*)&h2;
                sl[wv][3][px] = *(ushort*)&h3;
                sl[wv][4][px] = *(ushort*)&h4;
                sl[wv][5][px] = *(ushort*)&h5;
            }
            __builtin_amdgcn_wave_barrier();           // writes before reads

            #pragma unroll
            for (int m = 0; m < 2; ++m) {
                union { uint4 u; f16x8 v; } f0, f1, f2_, f3;
                const ushort* rdp = rbase + 64*m;
                f0.u  = *(const uint4*)(rdp);
                f1.u  = *(const uint4*)(rdp + 16);
                f2_.u = *(const uint4*)(rdp + 32);
                f3.u  = *(const uint4*)(rdp + 48);
                accA = __builtin_amdgcn_mfma_f32_32x32x16_f16(f0.v,  f0.v,  accA, 0, 0, 0);
                accB = __builtin_amdgcn_mfma_f32_32x32x16_f16(f1.v,  f1.v,  accB, 0, 0, 0);
                accA = __builtin_amdgcn_mfma_f32_32x32x16_f16(f2_.v, f2_.v, accA, 0, 0, 0);
                accB = __builtin_amdgcn_mfma_f32_32x32x16_f16(f3.v,  f3.v,  accB, 0, 0, 0);
            }
            __builtin_amdgcn_wave_barrier();           // next writes after reads
        }
    }

    if ((l & 31) < 7) {
        int j = l & 31;
        #pragma unroll
        for (int r = 0; r < 4; ++r) {
            int irow = r + 4*h;
            if (irow < 7) mom[wv][irow][j] = accA[r] + accB[r];
        }
    }
    __syncthreads();
    if (t < 27) {
        int a, b;
        if (t < 6) { a = t; b = 6; }                   // M1_a = Sum s_a * 1
        else {
            int rem = t - 6; a = 0;
            while (rem >= 6 - a) { rem -= 6 - a; ++a; }
            b = a + rem;
        }
        float v = mom[0][a][b] + mom[1][a][b] + mom[2][a][b] + mom[3][a][b];
        outp[t*2048 + blockIdx.x] = v;
    }
}

// ------- k_stats1: partial-reduce + BN1 fold -> A' fragment + w2pad (1 block) -------
__global__ __launch_bounds__(256) void k_stats1(const float* __restrict__ outp,
                                                const float* w1, const float* b1,
                                                const float* g1, const float* beta1,
                                                const float* w2, float* ws) {
    __shared__ float sm[32][8];
    __shared__ float redsm[27];
    int t = threadIdx.x;

    // phase A: reduce 27 x 2048 partials
    #pragma unroll 1
    for (int b = 0; b < 27; ++b) {
        float v = 0.f;
        #pragma unroll
        for (int k = 0; k < 8; ++k) v += outp[b*2048 + t + 256*k];
        for (int off = 32; off; off >>= 1) v += __shfl_xor(v, off);
        __shared__ float red4[4];
        if ((t & 63) == 0) red4[t >> 6] = v;
        __syncthreads();
        if (t == 0) redsm[b] = red4[0] + red4[1] + red4[2] + red4[3];
        __syncthreads();
    }
    if (t < 27) ws[t] = redsm[t];

    int c = t;
    if (c < 32) {
        #pragma unroll
        for (int k = 0; k < 8; ++k) sm[c][k] = 0.f;
        ws[64 + c] = (c < 25) ? w2[c] : 0.f;   // w2pad
    }
    __syncthreads();
    if (c < 25) {
        const float invN = 1.f / (float)NPIX;
        float m1[6], wr[6];
        #pragma unroll
        for (int i = 0; i < 6; ++i) m1[i] = redsm[i] * invN;
        #pragma unroll
        for (int i = 0; i < 6; ++i) wr[i] = w1[c*6 + i];
        float bc = b1[c];
        float mean = bc;
        #pragma unroll
        for (int i = 0; i < 6; ++i) mean = fmaf(wr[i], m1[i], mean);
        float e2 = bc * bc;
        #pragma unroll
        for (int i = 0; i < 6; ++i) e2 = fmaf(2.f*bc*wr[i], m1[i], e2);
        #pragma unroll
        for (int i = 0; i < 6; ++i)
            #pragma unroll
            for (int j = 0; j < 6; ++j) {
                int a = i < j ? i : j, b = i < j ? j : i;
                float m2 = redsm[6 + a*(11-a)/2 + b] * invN;
                e2 = fmaf(wr[i]*wr[j], m2, e2);
            }
        float var = e2 - mean*mean;
        float a1 = g1[c] * rsqrtf(var + BN_EPS);
        #pragma unroll
        for (int i = 0; i < 6; ++i) sm[c][i] = a1 * wr[i];
        sm[c][6] = fmaf(a1, bc - mean, beta1[c]);   // beff
    }
    __syncthreads();
    if (c < 64) {
        // A' = W1eff * D : coefficients on raw neighbors {C,N,S,E,W,NW,SE,1}
        int ch = c & 31, h = c >> 5;
        float aC=0.f, aN=0.f, aS=0.f, aE=0.f, aW=0.f, aNW=0.f, aSE=0.f, ab=0.f;
        if (h == 0) {
            float w0 = sm[ch][0], w1v = sm[ch][1], w2v = sm[ch][2];
            float w3 = sm[ch][3], w4v = sm[ch][4], w5 = sm[ch][5], be = sm[ch][6];
            aC  = w0 - 2.f*w3 - 2.f*w4v;
            aN  = -0.5f*w1v + w3;
            aS  =  0.5f*w1v + w3 - w5;
            aE  =  0.5f*w2v + w4v - w5;
            aW  = -0.5f*w2v + w4v;
            aNW = w5;
            aSE = w5;
            ab  = be;
        }
        __half2 p0 = __floats2half2_rn(aC,  aN);
        __half2 p1 = __floats2half2_rn(aS,  aE);
        __half2 p2 = __floats2half2_rn(aW,  aNW);
        __half2 p3 = __floats2half2_rn(aSE, ab);
        unsigned u0, u1, u2, u3;
        __builtin_memcpy(&u0, &p0, 4);
        __builtin_memcpy(&u1, &p1, 4);
        __builtin_memcpy(&u2, &p2, 4);
        __builtin_memcpy(&u3, &p3, 4);
        uint4 fr = {u0, u1, u2, u3};
        ((uint4*)(ws + 96))[c] = fr;
    }
}

// ------- k_main: MFMA conv on RAW neighbors (R17 scalar epilogue) -------
__global__ __launch_bounds__(256) void k_main(const float* __restrict__ x,
                                              const float* __restrict__ ws,
                                              const float* __restrict__ b2,
                                              float* __restrict__ stats,
                                              float* __restrict__ opre) {
    int t = threadIdx.x;
    int l = t & 63, wv = t >> 6;
    int lane31 = l & 31, h = l >> 5;
    const float* zb = ws + 1024;

    f16x8 afr;
    {
        uint4 u = ((const uint4*)(ws + 96))[l];
        union { uint4 u; f16x8 v; } cv; cv.u = u; afr = cv.v;
    }
    float w2v[16];
    #pragma unroll
    for (int r = 0; r < 16; ++r) {
        int creg = (r & 3) + 8 * (r >> 2);
        w2v[r] = ws[64 + creg + 4*h];
    }
    f32x16 zacc;
    #pragma unroll
    for (int r = 0; r < 16; ++r) zacc[r] = 0.f;
    float b2v = b2[0];
    float S1 = 0.f, S2 = 0.f;

    int wave_id = blockIdx.x * 4 + wv;        // 8192 waves x 2 rows
    #pragma unroll 1
    for (int rr = 0; rr < 2; ++rr) {
        int row = wave_id * 2 + rr;
        int i = row & 511;
        const float* xc = x + row * 512 + lane31;
        const float* xn = (i > 0)   ? xc - 512 : zb + lane31;
        const float* xs = (i < 511) ? xc + 512 : zb + lane31;
        float* op = opre + row * 512 + lane31;

        #pragma unroll
        for (int jt = 0; jt < 16; ++jt) {
            const int o4 = jt * 32;
            int offm1 = o4 - 1, offp1 = o4 + 1;
            if (jt == 0  && lane31 == 0)  offm1 = o4;   // OOB-safe clamp
            if (jt == 15 && lane31 == 31) offp1 = o4;

            float C  = xc[o4];
            float W_ = xc[offm1];
            float E  = xc[offp1];
            float N  = xn[o4];
            float NW = xn[offm1];
            float S_ = xs[o4];
            float SE = xs[offp1];
            if (jt == 0)  { bool ok = (lane31 != 0);  W_ = ok ? W_ : 0.f; NW = ok ? NW : 0.f; }
            if (jt == 15) { bool ok = (lane31 != 31); E  = ok ? E  : 0.f; SE = ok ? SE : 0.f; }

            __half2 p0 = __floats2half2_rn(C,  N);
            __half2 p1 = __floats2half2_rn(S_, E);
            __half2 p2 = __floats2half2_rn(W_, NW);
            __half2 p3 = __floats2half2_rn(SE, 1.f);
            unsigned u0, u1, u2, u3;
            __builtin_memcpy(&u0, &p0, 4);
            __builtin_memcpy(&u1, &p1, 4);
            __builtin_memcpy(&u2, &p2, 4);
            __builtin_memcpy(&u3, &p3, 4);
            union { uint4 u; f16x8 v; } bv;
            bv.u = (uint4){u0, u1, u2, u3};

            f32x16 acc = __builtin_amdgcn_mfma_f32_32x32x16_f16(afr, bv.v, zacc, 0, 0, 0);

            float o = 0.f;
            #pragma unroll
            for (int r = 0; r < 16; ++r)
                o = fmaf(fmaxf(acc[r], 0.f), w2v[r], o);
            o += __shfl_xor(o, 32);           // combine the two channel halves
            o += b2v;
            S1 += o;
            S2 = fmaf(o, o, S2);
            if (l < 32) op[o4] = o;
        }
    }

    for (int off = 32; off; off >>= 1) { S1 += __shfl_xor(S1, off); S2 += __shfl_xor(S2, off); }
    __shared__ float red[2][4];
    if (l == 0) { red[0][wv] = S1; red[1][wv] = S2; }
    __syncthreads();
    if (t == 0) stats[2048 + blockIdx.x] = 0.5f*(red[0][0]+red[0][1]+red[0][2]+red[0][3]);
    if (t == 1) stats[4096 + blockIdx.x] = 0.5f*(red[1][0]+red[1][1]+red[1][2]+red[1][3]);
}

// ------- k_redS: reduce S1/S2 partials into ws[27], ws[28] -------
__global__ __launch_bounds__(256) void k_redS(float* __restrict__ ws) {
    int t = threadIdx.x;
    float s1 = 0.f, s2 = 0.f;
    #pragma unroll
    for (int k = 0; k < 8; ++k) {
        s1 += ws[2048 + t + 256*k];
        s2 += ws[4096 + t + 256*k];
    }
    for (int off = 32; off; off >>= 1) { s1 += __shfl_xor(s1, off); s2 += __shfl_xor(s2, off); }
    __shared__ float red[2][4];
    int wave = t >> 6, lane = t & 63;
    if (lane == 0) { red[0][wave] = s1; red[1][wave] = s2; }
    __syncthreads();
    if (t == 0) ws[27] = red[0][0] + red[0][1] + red[0][2] + red[0][3];
    if (t == 1) ws[28] = red[1][0] + red[1][1] + red[1][2] + red[1][3];
}

// ---------------- k_final: BN2 fold computed inline ----------------
__global__ __launch_bounds__(256) void k_final(const float* __restrict__ x,
                                               const float* __restrict__ ws,
                                               const float* __restrict__ g2,
                                               const float* __restrict__ beta2,
                                               float* __restrict__ out) {
    const float invN = 1.f / (float)NPIX;
    float mean = ws[27] * invN;
    float var  = ws[28] * invN - mean*mean;
    float a2 = g2[0] * rsqrtf(var + BN_EPS);
    float c2 = fmaf(-mean, a2, beta2[0]);

    int idx = blockIdx.x * 256 + threadIdx.x;  // f4 index, 8192 blocks
    f4 o  = ((const f4*)out)[idx];
    f4 xv = ((const f4*)x)[idx];
    f4 r;
    r.x = fmaxf(fmaf(a2, o.x, c2), 0.f) + xv.x;
    r.y = fmaxf(fmaf(a2, o.y, c2), 0.f) + xv.y;
    r.z = fmaxf(fmaf(a2, o.z, c2), 0.f) + xv.z;
    r.w = fmaxf(fmaf(a2, o.w, c2), 0.f) + xv.w;
    ((f4*)out)[idx] = r;
}

extern "C" void kernel_launch(void* const* d_in, const int* in_sizes, int n_in,
                              void* d_out, int out_size, void* d_ws, size_t ws_size,
                              hipStream_t stream) {
    const float* x     = (const float*)d_in[0];
    const float* w1    = (const float*)d_in[1];
    const float* b1    = (const float*)d_in[2];
    const float* g1    = (const float*)d_in[3];
    const float* beta1 = (const float*)d_in[4];
    const float* w2    = (const float*)d_in[5];
    const float* b2    = (const float*)d_in[6];
    const float* g2    = (const float*)d_in[7];
    const float* beta2 = (const float*)d_in[8];
    float* out = (float*)d_out;
    float* ws  = (float*)d_ws;

    hipMemsetAsync(ws, 0, 8192, stream);
    k_moments<<<2048, 256, 0, stream>>>(x, ws, out);
    k_stats1 <<<1, 256, 0, stream>>>(out, w1, b1, g1, beta1, w2, ws);
    k_main   <<<2048, 256, 0, stream>>>(x, ws, b2, ws, out);
    k_redS   <<<1, 256, 0, stream>>>(ws);
    k_final  <<<8192, 256, 0, stream>>>(x, ws, g2, beta2, out);
}

// Round 20
// 92.762 us; speedup vs baseline: 1.2122x; 1.2122x over previous
//
#include <hip/hip_runtime.h>
#include <hip/hip_fp16.h>

typedef float f4 __attribute__((ext_vector_type(4)));
typedef float f2 __attribute__((ext_vector_type(2)));
typedef _Float16 f16x8 __attribute__((ext_vector_type(8)));
typedef float f32x16 __attribute__((ext_vector_type(16)));

#define NPIX (32*512*512)        // 8388608
#define BN_EPS 1e-5f

// ws float layout (memset clears first 8192 bytes = floats 0..2047):
// [0..26]   reduced M1/M2 moment sums (written by k_red)
// [27] S1, [28] S2 (written by k_redS)
// [64..95]  w2pad[32]
// [96..352) A'-fragment per lane: 64 x uint4 (f16x8 bit patterns)
// [1024]    zbuf rows (reads floats 1024..1535)
// S1 partials at ws[2048+bid], S2 partials at ws[4096+bid] (fully overwritten).
// opre (f16, 16MB) at byte offset 65536 of ws (d_ws is 256MB; poison-filled by harness).
// k_moments block partials live in d_out[i*2048 + bid] (overwritten by k_final later).

// ------- k_moments: MFMA Gram matrix of stencil channels -------
__global__ __launch_bounds__(256) void k_moments(const float* __restrict__ x,
                                                 const float* __restrict__ ws,
                                                 float* __restrict__ outp) {
    __shared__ ushort sl[4][8][64];   // [wave][channel][pixel] f16
    __shared__ float mom[4][7][7];
    int t = threadIdx.x;
    int l = t & 63, wv = t >> 6;
    int h = l >> 5;
    const float* zb = ws + 1024;

    sl[wv][6][l] = (ushort)0x3C00;    // 1.0h
    sl[wv][7][l] = (ushort)0;

    f32x16 accA, accB;
    #pragma unroll
    for (int r = 0; r < 16; ++r) { accA[r] = 0.f; accB[r] = 0.f; }

    int arow = ((l & 31) < 7) ? (l & 31) : 7;          // rows >=7 read the zero row
    const ushort* rdp = &sl[wv][arow][8*h];

    int wave_id = blockIdx.x * 4 + wv;                 // 8192 waves x 2 rows
    #pragma unroll 1
    for (int rr = 0; rr < 2; ++rr) {
        int row = wave_id * 2 + rr;
        int i = row & 511;
        const float* xr = x + row * 512;
        const float* xn = (i > 0)   ? xr - 512 : zb;
        const float* xs = (i < 511) ? xr + 512 : zb;
        #pragma unroll 1
        for (int it = 0; it < 8; ++it) {
            int col = it * 64 + l;
            bool okw = (col > 0), oke = (col < 511);
            int cm = okw ? col - 1 : 0;
            int cp = oke ? col + 1 : 511;
            float C  = xr[col], N = xn[col], S_ = xs[col];
            float W_ = xr[cm],  E = xr[cp];
            float NW = xn[cm],  SE = xs[cp];
            W_ = okw ? W_ : 0.f; NW = okw ? NW : 0.f;
            E  = oke ? E  : 0.f; SE = oke ? SE : 0.f;

            float s0 = C;
            float s1 = (S_ - N) * 0.5f;
            float s2 = (E - W_) * 0.5f;
            float s3 = S_ + N - 2.f*C;
            float s4 = E + W_ - 2.f*C;
            float s5 = SE + NW - S_ - E;

            __half h0 = __float2half(s0), h1 = __float2half(s1);
            __half h2 = __float2half(s2), h3 = __float2half(s3);
            __half h4 = __float2half(s4), h5 = __float2half(s5);
            sl[wv][0][l] = *(ushort*)&h0;
            sl[wv][1][l] = *(ushort*)&h1;
            sl[wv][2][l] = *(ushort*)&h2;
            sl[wv][3][l] = *(ushort*)&h3;
            sl[wv][4][l] = *(ushort*)&h4;
            sl[wv][5][l] = *(ushort*)&h5;
            __builtin_amdgcn_wave_barrier();           // order writes before reads

            union { uint4 u; f16x8 v; } f0, f1, f2_, f3;
            f0.u  = *(const uint4*)(rdp);
            f1.u  = *(const uint4*)(rdp + 16);
            f2_.u = *(const uint4*)(rdp + 32);
            f3.u  = *(const uint4*)(rdp + 48);
            accA = __builtin_amdgcn_mfma_f32_32x32x16_f16(f0.v,  f0.v,  accA, 0, 0, 0);
            accB = __builtin_amdgcn_mfma_f32_32x32x16_f16(f1.v,  f1.v,  accB, 0, 0, 0);
            accA = __builtin_amdgcn_mfma_f32_32x32x16_f16(f2_.v, f2_.v, accA, 0, 0, 0);
            accB = __builtin_amdgcn_mfma_f32_32x32x16_f16(f3.v,  f3.v,  accB, 0, 0, 0);
            __builtin_amdgcn_wave_barrier();           // keep next writes after reads
        }
    }

    if ((l & 31) < 7) {
        int j = l & 31;
        #pragma unroll
        for (int r = 0; r < 4; ++r) {
            int irow = r + 4*h;
            if (irow < 7) mom[wv][irow][j] = accA[r] + accB[r];
        }
    }
    __syncthreads();
    if (t < 27) {
        int a, b;
        if (t < 6) { a = t; b = 6; }                   // M1_a = Sum s_a * 1
        else {
            int rem = t - 6; a = 0;
            while (rem >= 6 - a) { rem -= 6 - a; ++a; }
            b = a + rem;
        }
        float v = mom[0][a][b] + mom[1][a][b] + mom[2][a][b] + mom[3][a][b];
        outp[t*2048 + blockIdx.x] = v;
    }
}

// ------- k_red: reduce 27 x 2048 partials from d_out into ws[0..26] -------
__global__ __launch_bounds__(256) void k_red(const float* __restrict__ outp,
                                             float* __restrict__ ws) {
    int b = blockIdx.x;                        // 0..26
    int t = threadIdx.x;
    float v = 0.f;
    #pragma unroll
    for (int k = 0; k < 8; ++k) v += outp[b*2048 + t + 256*k];
    for (int off = 32; off; off >>= 1) v += __shfl_xor(v, off);
    __shared__ float red[4];
    int wave = t >> 6, lane = t & 63;
    if (lane == 0) red[wave] = v;
    __syncthreads();
    if (t == 0) ws[b] = red[0] + red[1] + red[2] + red[3];
}

// ------- k_stats1: BN1 fold -> A' = W1eff*D fragment + w2pad (64 threads) -------
__global__ void k_stats1(const float* w1, const float* b1, const float* g1,
                         const float* beta1, const float* w2, float* ws) {
    __shared__ float sm[32][8];
    int c = threadIdx.x;                       // 0..63
    if (c < 32) {
        #pragma unroll
        for (int k = 0; k < 8; ++k) sm[c][k] = 0.f;
        ws[64 + c] = (c < 25) ? w2[c] : 0.f;   // w2pad
    }
    __syncthreads();
    if (c < 25) {
        const float invN = 1.f / (float)NPIX;
        float m1[6], wr[6];
        #pragma unroll
        for (int i = 0; i < 6; ++i) m1[i] = ws[i] * invN;
        #pragma unroll
        for (int i = 0; i < 6; ++i) wr[i] = w1[c*6 + i];
        float bc = b1[c];
        float mean = bc;
        #pragma unroll
        for (int i = 0; i < 6; ++i) mean = fmaf(wr[i], m1[i], mean);
        float e2 = bc * bc;
        #pragma unroll
        for (int i = 0; i < 6; ++i) e2 = fmaf(2.f*bc*wr[i], m1[i], e2);
        #pragma unroll
        for (int i = 0; i < 6; ++i)
            #pragma unroll
            for (int j = 0; j < 6; ++j) {
                int a = i < j ? i : j, b = i < j ? j : i;
                float m2 = ws[6 + a*(11-a)/2 + b] * invN;
                e2 = fmaf(wr[i]*wr[j], m2, e2);
            }
        float var = e2 - mean*mean;
        float a1 = g1[c] * rsqrtf(var + BN_EPS);
        #pragma unroll
        for (int i = 0; i < 6; ++i) sm[c][i] = a1 * wr[i];
        sm[c][6] = fmaf(a1, bc - mean, beta1[c]);   // beff
    }
    __syncthreads();
    // A' = W1eff * D : coefficients on raw neighbors {C,N,S,E,W,NW,SE,1}
    int ch = c & 31, h = c >> 5;
    float aC=0.f, aN=0.f, aS=0.f, aE=0.f, aW=0.f, aNW=0.f, aSE=0.f, ab=0.f;
    if (h == 0) {
        float w0 = sm[ch][0], w1v = sm[ch][1], w2v = sm[ch][2];
        float w3 = sm[ch][3], w4v = sm[ch][4], w5 = sm[ch][5], be = sm[ch][6];
        aC  = w0 - 2.f*w3 - 2.f*w4v;
        aN  = -0.5f*w1v + w3;
        aS  =  0.5f*w1v + w3 - w5;
        aE  =  0.5f*w2v + w4v - w5;
        aW  = -0.5f*w2v + w4v;
        aNW = w5;
        aSE = w5;
        ab  = be;
    }
    __half2 p0 = __floats2half2_rn(aC,  aN);
    __half2 p1 = __floats2half2_rn(aS,  aE);
    __half2 p2 = __floats2half2_rn(aW,  aNW);
    __half2 p3 = __floats2half2_rn(aSE, ab);
    unsigned u0, u1, u2, u3;
    __builtin_memcpy(&u0, &p0, 4);
    __builtin_memcpy(&u1, &p1, 4);
    __builtin_memcpy(&u2, &p2, 4);
    __builtin_memcpy(&u3, &p3, 4);
    uint4 fr = {u0, u1, u2, u3};
    ((uint4*)(ws + 96))[c] = fr;
}

// ------- k_main: MFMA conv on RAW neighbors, scalar epilogue, f16 opre -------
__global__ __launch_bounds__(256) void k_main(const float* __restrict__ x,
                                              const float* __restrict__ ws,
                                              const float* __restrict__ b2,
                                              float* __restrict__ stats,
                                              __half* __restrict__ oph) {
    int t = threadIdx.x;
    int l = t & 63, wv = t >> 6;
    int lane31 = l & 31, h = l >> 5;
    const float* zb = ws + 1024;

    f16x8 afr;
    {
        uint4 u = ((const uint4*)(ws + 96))[l];
        union { uint4 u; f16x8 v; } cv; cv.u = u; afr = cv.v;
    }
    float w2v[16];
    #pragma unroll
    for (int r = 0; r < 16; ++r) {
        int creg = (r & 3) + 8 * (r >> 2);
        w2v[r] = ws[64 + creg + 4*h];
    }
    f32x16 zacc;
    #pragma unroll
    for (int r = 0; r < 16; ++r) zacc[r] = 0.f;
    float b2v = b2[0];
    float S1 = 0.f, S2 = 0.f;

    int wave_id = blockIdx.x * 4 + wv;        // 8192 waves x 2 rows
    #pragma unroll 1
    for (int rr = 0; rr < 2; ++rr) {
        int row = wave_id * 2 + rr;
        int i = row & 511;
        const float* xc = x + row * 512 + lane31;
        const float* xn = (i > 0)   ? xc - 512 : zb + lane31;
        const float* xs = (i < 511) ? xc + 512 : zb + lane31;
        __half* op = oph + row * 512 + lane31;

        #pragma unroll
        for (int jt = 0; jt < 16; ++jt) {
            const int o4 = jt * 32;
            int offm1 = o4 - 1, offp1 = o4 + 1;
            if (jt == 0  && lane31 == 0)  offm1 = o4;   // OOB-safe clamp
            if (jt == 15 && lane31 == 31) offp1 = o4;

            float C  = xc[o4];
            float W_ = xc[offm1];
            float E  = xc[offp1];
            float N  = xn[o4];
            float NW = xn[offm1];
            float S_ = xs[o4];
            float SE = xs[offp1];
            if (jt == 0)  { bool ok = (lane31 != 0);  W_ = ok ? W_ : 0.f; NW = ok ? NW : 0.f; }
            if (jt == 15) { bool ok = (lane31 != 31); E  = ok ? E  : 0.f; SE = ok ? SE : 0.f; }

            __half2 p0 = __floats2half2_rn(C,  N);
            __half2 p1 = __floats2half2_rn(S_, E);
            __half2 p2 = __floats2half2_rn(W_, NW);
            __half2 p3 = __floats2half2_rn(SE, 1.f);
            unsigned u0, u1, u2, u3;
            __builtin_memcpy(&u0, &p0, 4);
            __builtin_memcpy(&u1, &p1, 4);
            __builtin_memcpy(&u2, &p2, 4);
            __builtin_memcpy(&u3, &p3, 4);
            union { uint4 u; f16x8 v; } bv;
            bv.u = (uint4){u0, u1, u2, u3};

            f32x16 acc = __builtin_amdgcn_mfma_f32_32x32x16_f16(afr, bv.v, zacc, 0, 0, 0);

            float o = 0.f;
            #pragma unroll
            for (int r = 0; r < 16; ++r)
                o = fmaf(fmaxf(acc[r], 0.f), w2v[r], o);
            o += __shfl_xor(o, 32);           // combine the two channel halves
            o += b2v;
            S1 += o;
            S2 = fmaf(o, o, S2);
            if (l < 32) op[o4] = __float2half(o);
        }
    }

    for (int off = 32; off; off >>= 1) { S1 += __shfl_xor(S1, off); S2 += __shfl_xor(S2, off); }
    __shared__ float red[2][4];
    if (l == 0) { red[0][wv] = S1; red[1][wv] = S2; }
    __syncthreads();
    if (t == 0) stats[2048 + blockIdx.x] = 0.5f*(red[0][0]+red[0][1]+red[0][2]+red[0][3]);
    if (t == 1) stats[4096 + blockIdx.x] = 0.5f*(red[1][0]+red[1][1]+red[1][2]+red[1][3]);
}

// ------- k_redS: reduce S1/S2 partials into ws[27], ws[28] -------
__global__ __launch_bounds__(256) void k_redS(float* __restrict__ ws) {
    int t = threadIdx.x;
    float s1 = 0.f, s2 = 0.f;
    #pragma unroll
    for (int k = 0; k < 8; ++k) {
        s1 += ws[2048 + t + 256*k];
        s2 += ws[4096 + t + 256*k];
    }
    for (int off = 32; off; off >>= 1) { s1 += __shfl_xor(s1, off); s2 += __shfl_xor(s2, off); }
    __shared__ float red[2][4];
    int wave = t >> 6, lane = t & 63;
    if (lane == 0) { red[0][wave] = s1; red[1][wave] = s2; }
    __syncthreads();
    if (t == 0) ws[27] = red[0][0] + red[0][1] + red[0][2] + red[0][3];
    if (t == 1) ws[28] = red[1][0] + red[1][1] + red[1][2] + red[1][3];
}

// ---------------- k_final: BN2 fold inline, f16 opre read ----------------
__global__ __launch_bounds__(256) void k_final(const float* __restrict__ x,
                                               const float* __restrict__ ws,
                                               const __half* __restrict__ oph,
                                               const float* __restrict__ g2,
                                               const float* __restrict__ beta2,
                                               float* __restrict__ out) {
    const float invN = 1.f / (float)NPIX;
    float mean = ws[27] * invN;
    float var  = ws[28] * invN - mean*mean;
    float a2 = g2[0] * rsqrtf(var + BN_EPS);
    float c2 = fmaf(-mean, a2, beta2[0]);

    int idx = blockIdx.x * 256 + threadIdx.x;  // f4 index, 8192 blocks
    uint2 u = ((const uint2*)oph)[idx];
    __half2 h01, h23;
    __builtin_memcpy(&h01, &u.x, 4);
    __builtin_memcpy(&h23, &u.y, 4);
    float2 f01 = __half22float2(h01);
    float2 f23 = __half22float2(h23);
    f4 xv = ((const f4*)x)[idx];
    f4 r;
    r.x = fmaxf(fmaf(a2, f01.x, c2), 0.f) + xv.x;
    r.y = fmaxf(fmaf(a2, f01.y, c2), 0.f) + xv.y;
    r.z = fmaxf(fmaf(a2, f23.x, c2), 0.f) + xv.z;
    r.w = fmaxf(fmaf(a2, f23.y, c2), 0.f) + xv.w;
    ((f4*)out)[idx] = r;
}

extern "C" void kernel_launch(void* const* d_in, const int* in_sizes, int n_in,
                              void* d_out, int out_size, void* d_ws, size_t ws_size,
                              hipStream_t stream) {
    const float* x     = (const float*)d_in[0];
    const float* w1    = (const float*)d_in[1];
    const float* b1    = (const float*)d_in[2];
    const float* g1    = (const float*)d_in[3];
    const float* beta1 = (const float*)d_in[4];
    const float* w2    = (const float*)d_in[5];
    const float* b2    = (const float*)d_in[6];
    const float* g2    = (const float*)d_in[7];
    const float* beta2 = (const float*)d_in[8];
    float* out = (float*)d_out;
    float* ws  = (float*)d_ws;
    __half* oph = (__half*)((char*)d_ws + 65536);   // 16MB f16 opre region

    hipMemsetAsync(ws, 0, 8192, stream);
    k_moments<<<2048, 256, 0, stream>>>(x, ws, out);
    k_red    <<<27, 256, 0, stream>>>(out, ws);
    k_stats1 <<<1, 64, 0, stream>>>(w1, b1, g1, beta1, w2, ws);
    k_main   <<<2048, 256, 0, stream>>>(x, ws, b2, ws, oph);
    k_redS   <<<1, 256, 0, stream>>>(ws);
    k_final  <<<8192, 256, 0, stream>>>(x, ws, oph, g2, beta2, out);
}

// Round 21
// 86.967 us; speedup vs baseline: 1.2930x; 1.0666x over previous
//
#include <hip/hip_runtime.h>
#include <hip/hip_fp16.h>

typedef float f4 __attribute__((ext_vector_type(4)));
typedef float f2 __attribute__((ext_vector_type(2)));
typedef _Float16 f16x8 __attribute__((ext_vector_type(8)));
typedef float f32x16 __attribute__((ext_vector_type(16)));

#define NPIX (32*512*512)        // 8388608
#define BN_EPS 1e-5f

// ws float layout (memset clears first 8192 bytes = floats 0..2047):
// [0..35]   reduced raw-Gram sums G[a<=b], a,b in 0..7 (by k_red)
// [27]..    (unused legacy slots ok) ; S1 at [40], S2 at [41] via k_redS
// [64..95]  w2pad[32]
// [96..352) A'-fragment per lane: 64 x uint4 (f16x8 bit patterns)
// [1024]    zbuf rows (reads floats 1024..1535)
// S1 partials at ws[2048+bid], S2 partials at ws[4096+bid] (fully overwritten).
// opre (f16, 16MB) at byte offset 65536 of ws.
// k_moments block partials live in d_out[t*2048 + bid] (overwritten by k_final).

// ------- k_moments: MFMA Gram of RAW neighbor vector {C,N,S,E,W,NW,SE,1} -------
__global__ __launch_bounds__(256) void k_moments(const float* __restrict__ x,
                                                 const float* __restrict__ ws,
                                                 float* __restrict__ outp) {
    __shared__ ushort sl[4][9][136];  // [wave][row][px] f16; rows 0..6 data, 7 ones, 8 zero
    __shared__ float mom[4][8][8];
    int t = threadIdx.x;
    int l = t & 63, wv = t >> 6;
    int h = l >> 5;
    const float* zb = ws + 1024;

    // static rows
    sl[wv][7][l]      = (ushort)0x3C00;  // 1.0h
    sl[wv][7][l + 64] = (ushort)0x3C00;
    sl[wv][8][l]      = (ushort)0;
    sl[wv][8][l + 64] = (ushort)0;

    f32x16 accA, accB;
    #pragma unroll
    for (int r = 0; r < 16; ++r) { accA[r] = 0.f; accB[r] = 0.f; }

    int a31 = l & 31;
    int arow = (a31 < 8) ? a31 : 8;               // rows >=8 read the zero row
    const ushort* rdp = &sl[wv][arow][8*h];

    int wave_id = blockIdx.x * 4 + wv;            // 8192 waves x 2 rows
    #pragma unroll 1
    for (int rr = 0; rr < 2; ++rr) {
        int row = wave_id * 2 + rr;
        int i = row & 511;
        const float* xr = x + row * 512;
        const float* xn = (i > 0)   ? xr - 512 : zb;
        const float* xs = (i < 511) ? xr + 512 : zb;
        #pragma unroll 1
        for (int p4 = 0; p4 < 4; ++p4) {          // 4 panes of 128 px
            int c0 = p4 * 128 + 2 * l;            // even column
            f2 C  = *(const f2*)(xr + c0);
            f2 N_ = *(const f2*)(xn + c0);
            f2 S_ = *(const f2*)(xs + c0);
            bool okw = (c0 > 0), oke = (c0 < 510);
            int cm = okw ? c0 - 1 : c0;           // OOB-safe clamp
            int cp = oke ? c0 + 2 : c0;
            float Wlo  = xr[cm];  Wlo  = okw ? Wlo  : 0.f;
            float Ehi  = xr[cp];  Ehi  = oke ? Ehi  : 0.f;
            float NWlo = xn[cm];  NWlo = okw ? NWlo : 0.f;
            float SEhi = xs[cp];  SEhi = oke ? SEhi : 0.f;

            __half2 q0 = __floats2half2_rn(C.x,  C.y);
            __half2 q1 = __floats2half2_rn(N_.x, N_.y);
            __half2 q2 = __floats2half2_rn(S_.x, S_.y);
            __half2 q3 = __floats2half2_rn(C.y,  Ehi);    // E = {C.y, Ehi}
            __half2 q4 = __floats2half2_rn(Wlo,  C.x);    // W = {Wlo, C.x}
            __half2 q5 = __floats2half2_rn(NWlo, N_.x);   // NW
            __half2 q6 = __floats2half2_rn(S_.y, SEhi);   // SE
            unsigned v0,v1,v2,v3,v4,v5,v6;
            __builtin_memcpy(&v0,&q0,4); __builtin_memcpy(&v1,&q1,4);
            __builtin_memcpy(&v2,&q2,4); __builtin_memcpy(&v3,&q3,4);
            __builtin_memcpy(&v4,&q4,4); __builtin_memcpy(&v5,&q5,4);
            __builtin_memcpy(&v6,&q6,4);
            *(unsigned*)&sl[wv][0][2*l] = v0;
            *(unsigned*)&sl[wv][1][2*l] = v1;
            *(unsigned*)&sl[wv][2][2*l] = v2;
            *(unsigned*)&sl[wv][3][2*l] = v3;
            *(unsigned*)&sl[wv][4][2*l] = v4;
            *(unsigned*)&sl[wv][5][2*l] = v5;
            *(unsigned*)&sl[wv][6][2*l] = v6;
            __builtin_amdgcn_wave_barrier();      // writes before reads

            #pragma unroll
            for (int w16 = 0; w16 < 8; w16 += 2) {
                union { uint4 u; f16x8 v; } fa, fb;
                fa.u = *(const uint4*)(rdp + w16*16);
                fb.u = *(const uint4*)(rdp + w16*16 + 16);
                accA = __builtin_amdgcn_mfma_f32_32x32x16_f16(fa.v, fa.v, accA, 0, 0, 0);
                accB = __builtin_amdgcn_mfma_f32_32x32x16_f16(fb.v, fb.v, accB, 0, 0, 0);
            }
            __builtin_amdgcn_wave_barrier();      // next writes after reads
        }
    }

    // D layout: col=lane&31, row=(r&3)+8*(r>>2)+4h ; rows 0..7 come from r=0..3
    if (a31 < 8) {
        #pragma unroll
        for (int r = 0; r < 4; ++r)
            mom[wv][r + 4*h][a31] = accA[r] + accB[r];
    }
    __syncthreads();
    if (t < 36) {
        int a = 0, rem = t;
        while (rem >= 8 - a) { rem -= 8 - a; ++a; }
        int b = a + rem;
        float v = mom[0][a][b] + mom[1][a][b] + mom[2][a][b] + mom[3][a][b];
        outp[t*2048 + blockIdx.x] = v;
    }
}

// ------- k_red: reduce 36 x 2048 partials from d_out into ws[0..35] -------
__global__ __launch_bounds__(256) void k_red(const float* __restrict__ outp,
                                             float* __restrict__ ws) {
    int b = blockIdx.x;                        // 0..35
    int t = threadIdx.x;
    float v = 0.f;
    #pragma unroll
    for (int k = 0; k < 8; ++k) v += outp[b*2048 + t + 256*k];
    for (int off = 32; off; off >>= 1) v += __shfl_xor(v, off);
    __shared__ float red[4];
    int wave = t >> 6, lane = t & 63;
    if (lane == 0) red[wave] = v;
    __syncthreads();
    if (t == 0) ws[b] = red[0] + red[1] + red[2] + red[3];
}

// ------- k_stats1: raw-Gram -> BN1 stats -> A' fragment + w2pad (64 threads) -------
__global__ void k_stats1(const float* w1, const float* b1, const float* g1,
                         const float* beta1, const float* w2, float* ws) {
    __shared__ float sm[32][8];                // scaled raw coefficients per channel
    __shared__ float G[8][8];
    int c = threadIdx.x;                       // 0..63
    if (c < 32) {
        #pragma unroll
        for (int k = 0; k < 8; ++k) sm[c][k] = 0.f;
        ws[64 + c] = (c < 25) ? w2[c] : 0.f;   // w2pad
    }
    if (c < 36) {
        int a = 0, rem = c;
        while (rem >= 8 - a) { rem -= 8 - a; ++a; }
        int b = a + rem;
        float v = ws[c];
        G[a][b] = v; G[b][a] = v;
    }
    __syncthreads();
    if (c < 25) {
        const float invN = 1.f / (float)NPIX;
        float wr[6];
        #pragma unroll
        for (int i = 0; i < 6; ++i) wr[i] = w1[c*6 + i];
        float bc = b1[c];
        // raw-basis coefficients Wt = D^T w1 (+bias on ones slot)
        float Wt[8];
        Wt[0] = wr[0] - 2.f*wr[3] - 2.f*wr[4];        // C
        Wt[1] = -0.5f*wr[1] + wr[3];                  // N
        Wt[2] =  0.5f*wr[1] + wr[3] - wr[5];          // S
        Wt[3] =  0.5f*wr[2] + wr[4] - wr[5];          // E
        Wt[4] = -0.5f*wr[2] + wr[4];                  // W
        Wt[5] = wr[5];                                // NW
        Wt[6] = wr[5];                                // SE
        Wt[7] = bc;                                   // ones
        float mean = 0.f;
        #pragma unroll
        for (int k = 0; k < 8; ++k) mean = fmaf(Wt[k], G[k][7], mean);
        mean *= invN;
        float e2 = 0.f;
        #pragma unroll
        for (int k = 0; k < 8; ++k) {
            float rd = 0.f;
            #pragma unroll
            for (int m = 0; m < 8; ++m) rd = fmaf(Wt[m], G[k][m], rd);
            e2 = fmaf(Wt[k], rd, e2);
        }
        e2 *= invN;
        float var = e2 - mean*mean;
        float a1 = g1[c] * rsqrtf(var + BN_EPS);
        #pragma unroll
        for (int k = 0; k < 7; ++k) sm[c][k] = a1 * Wt[k];
        sm[c][7] = fmaf(a1, bc - mean, beta1[c]);     // ones-slot: a1*b1 + beta - a1*mean
    }
    __syncthreads();
    // pack A' fragment: k-order {C,N},{S,E},{W,NW},{SE,1}; h=1 half zero
    int ch = c & 31, h = c >> 5;
    float aC=0.f, aN=0.f, aS=0.f, aE=0.f, aW=0.f, aNW=0.f, aSE=0.f, ab=0.f;
    if (h == 0) {
        aC = sm[ch][0]; aN = sm[ch][1]; aS = sm[ch][2]; aE = sm[ch][3];
        aW = sm[ch][4]; aNW = sm[ch][5]; aSE = sm[ch][6]; ab = sm[ch][7];
    }
    __half2 p0 = __floats2half2_rn(aC,  aN);
    __half2 p1 = __floats2half2_rn(aS,  aE);
    __half2 p2 = __floats2half2_rn(aW,  aNW);
    __half2 p3 = __floats2half2_rn(aSE, ab);
    unsigned u0, u1, u2, u3;
    __builtin_memcpy(&u0, &p0, 4);
    __builtin_memcpy(&u1, &p1, 4);
    __builtin_memcpy(&u2, &p2, 4);
    __builtin_memcpy(&u3, &p3, 4);
    uint4 fr = {u0, u1, u2, u3};
    ((uint4*)(ws + 96))[c] = fr;
}

// ------- k_main: MFMA conv on RAW neighbors, scalar epilogue (r<13), f16 opre -------
__global__ __launch_bounds__(256) void k_main(const float* __restrict__ x,
                                              const float* __restrict__ ws,
                                              const float* __restrict__ b2,
                                              float* __restrict__ stats,
                                              __half* __restrict__ oph) {
    int t = threadIdx.x;
    int l = t & 63, wv = t >> 6;
    int lane31 = l & 31, h = l >> 5;
    const float* zb = ws + 1024;

    f16x8 afr;
    {
        uint4 u = ((const uint4*)(ws + 96))[l];
        union { uint4 u; f16x8 v; } cv; cv.u = u; afr = cv.v;
    }
    float w2v[13];
    #pragma unroll
    for (int r = 0; r < 13; ++r) {
        int creg = (r & 3) + 8 * (r >> 2);
        w2v[r] = ws[64 + creg + 4*h];          // h=1,r=12 -> w2pad[28]=0
    }
    f32x16 zacc;
    #pragma unroll
    for (int r = 0; r < 16; ++r) zacc[r] = 0.f;
    float b2v = b2[0];
    float S1 = 0.f, S2 = 0.f;

    int wave_id = blockIdx.x * 4 + wv;        // 8192 waves x 2 rows
    #pragma unroll 1
    for (int rr = 0; rr < 2; ++rr) {
        int row = wave_id * 2 + rr;
        int i = row & 511;
        const float* xc = x + row * 512 + lane31;
        const float* xn = (i > 0)   ? xc - 512 : zb + lane31;
        const float* xs = (i < 511) ? xc + 512 : zb + lane31;
        __half* op = oph + row * 512 + lane31;

        #pragma unroll
        for (int jt = 0; jt < 16; ++jt) {
            const int o4 = jt * 32;
            int offm1 = o4 - 1, offp1 = o4 + 1;
            if (jt == 0  && lane31 == 0)  offm1 = o4;   // OOB-safe clamp
            if (jt == 15 && lane31 == 31) offp1 = o4;

            float C  = xc[o4];
            float W_ = xc[offm1];
            float E  = xc[offp1];
            float N  = xn[o4];
            float NW = xn[offm1];
            float S_ = xs[o4];
            float SE = xs[offp1];
            if (jt == 0)  { bool ok = (lane31 != 0);  W_ = ok ? W_ : 0.f; NW = ok ? NW : 0.f; }
            if (jt == 15) { bool ok = (lane31 != 31); E  = ok ? E  : 0.f; SE = ok ? SE : 0.f; }

            __half2 p0 = __floats2half2_rn(C,  N);
            __half2 p1 = __floats2half2_rn(S_, E);
            __half2 p2 = __floats2half2_rn(W_, NW);
            __half2 p3 = __floats2half2_rn(SE, 1.f);
            unsigned u0, u1, u2, u3;
            __builtin_memcpy(&u0, &p0, 4);
            __builtin_memcpy(&u1, &p1, 4);
            __builtin_memcpy(&u2, &p2, 4);
            __builtin_memcpy(&u3, &p3, 4);
            union { uint4 u; f16x8 v; } bv;
            bv.u = (uint4){u0, u1, u2, u3};

            f32x16 acc = __builtin_amdgcn_mfma_f32_32x32x16_f16(afr, bv.v, zacc, 0, 0, 0);

            float o = 0.f;
            #pragma unroll
            for (int r = 0; r < 13; ++r)       // channels >=25 are exact zeros
                o = fmaf(fmaxf(acc[r], 0.f), w2v[r], o);
            o += __shfl_xor(o, 32);            // combine the two channel halves
            o += b2v;
            S1 += o;
            S2 = fmaf(o, o, S2);
            if (l < 32) op[o4] = __float2half(o);
        }
    }

    for (int off = 32; off; off >>= 1) { S1 += __shfl_xor(S1, off); S2 += __shfl_xor(S2, off); }
    __shared__ float red[2][4];
    if (l == 0) { red[0][wv] = S1; red[1][wv] = S2; }
    __syncthreads();
    if (t == 0) stats[2048 + blockIdx.x] = 0.5f*(red[0][0]+red[0][1]+red[0][2]+red[0][3]);
    if (t == 1) stats[4096 + blockIdx.x] = 0.5f*(red[1][0]+red[1][1]+red[1][2]+red[1][3]);
}

// ------- k_redS: reduce S1/S2 partials into ws[40], ws[41] -------
__global__ __launch_bounds__(256) void k_redS(float* __restrict__ ws) {
    int t = threadIdx.x;
    float s1 = 0.f, s2 = 0.f;
    #pragma unroll
    for (int k = 0; k < 8; ++k) {
        s1 += ws[2048 + t + 256*k];
        s2 += ws[4096 + t + 256*k];
    }
    for (int off = 32; off; off >>= 1) { s1 += __shfl_xor(s1, off); s2 += __shfl_xor(s2, off); }
    __shared__ float red[2][4];
    int wave = t >> 6, lane = t & 63;
    if (lane == 0) { red[0][wave] = s1; red[1][wave] = s2; }
    __syncthreads();
    if (t == 0) ws[40] = red[0][0] + red[0][1] + red[0][2] + red[0][3];
    if (t == 1) ws[41] = red[1][0] + red[1][1] + red[1][2] + red[1][3];
}

// ---------------- k_final: BN2 fold inline, f16 opre read ----------------
__global__ __launch_bounds__(256) void k_final(const float* __restrict__ x,
                                               const float* __restrict__ ws,
                                               const __half* __restrict__ oph,
                                               const float* __restrict__ g2,
                                               const float* __restrict__ beta2,
                                               float* __restrict__ out) {
    const float invN = 1.f / (float)NPIX;
    float mean = ws[40] * invN;
    float var  = ws[41] * invN - mean*mean;
    float a2 = g2[0] * rsqrtf(var + BN_EPS);
    float c2 = fmaf(-mean, a2, beta2[0]);

    int idx = blockIdx.x * 256 + threadIdx.x;  // f4 index, 8192 blocks
    uint2 u = ((const uint2*)oph)[idx];
    __half2 h01, h23;
    __builtin_memcpy(&h01, &u.x, 4);
    __builtin_memcpy(&h23, &u.y, 4);
    float2 f01 = __half22float2(h01);
    float2 f23 = __half22float2(h23);
    f4 xv = ((const f4*)x)[idx];
    f4 r;
    r.x = fmaxf(fmaf(a2, f01.x, c2), 0.f) + xv.x;
    r.y = fmaxf(fmaf(a2, f01.y, c2), 0.f) + xv.y;
    r.z = fmaxf(fmaf(a2, f23.x, c2), 0.f) + xv.z;
    r.w = fmaxf(fmaf(a2, f23.y, c2), 0.f) + xv.w;
    ((f4*)out)[idx] = r;
}

extern "C" void kernel_launch(void* const* d_in, const int* in_sizes, int n_in,
                              void* d_out, int out_size, void* d_ws, size_t ws_size,
                              hipStream_t stream) {
    const float* x     = (const float*)d_in[0];
    const float* w1    = (const float*)d_in[1];
    const float* b1    = (const float*)d_in[2];
    const float* g1    = (const float*)d_in[3];
    const float* beta1 = (const float*)d_in[4];
    const float* w2    = (const float*)d_in[5];
    const float* b2    = (const float*)d_in[6];
    const float* g2    = (const float*)d_in[7];
    const float* beta2 = (const float*)d_in[8];
    float* out = (float*)d_out;
    float* ws  = (float*)d_ws;
    __half* oph = (__half*)((char*)d_ws + 65536);   // 16MB f16 opre region

    hipMemsetAsync(ws, 0, 8192, stream);
    k_moments<<<2048, 256, 0, stream>>>(x, ws, out);
    k_red    <<<36, 256, 0, stream>>>(out, ws);
    k_stats1 <<<1, 64, 0, stream>>>(w1, b1, g1, beta1, w2, ws);
    k_main   <<<2048, 256, 0, stream>>>(x, ws, b2, ws, oph);
    k_redS   <<<1, 256, 0, stream>>>(ws);
    k_final  <<<8192, 256, 0, stream>>>(x, ws, oph, g2, beta2, out);
}